// Round 5
// baseline (132.693 us; speedup 1.0000x reference)
//
#include <hip/hip_runtime.h>
#include <hip/hip_bf16.h>

#define S_LEN 2048
#define E_DIM 1024
#define NH 16
#define HD 64
#define ATTN_SCALE 0.03125f   // 1/sqrt(1024)
#define KVB 128

typedef __attribute__((ext_vector_type(8))) short short8;
typedef __attribute__((ext_vector_type(8))) unsigned short ushort8;
typedef __attribute__((ext_vector_type(4))) unsigned short ushort4_t;
typedef __attribute__((ext_vector_type(4))) float f32x4;
typedef __attribute__((ext_vector_type(4))) float f4;

__device__ __forceinline__ float bf2f(unsigned short u) {
    unsigned int x = ((unsigned int)u) << 16;
    return __builtin_bit_cast(float, x);
}
__device__ __forceinline__ unsigned short f2bf(float f) {
    unsigned int x = __builtin_bit_cast(unsigned int, f);
    x += 0x7FFFu + ((x >> 16) & 1u);   // RNE
    return (unsigned short)(x >> 16);
}
__device__ __forceinline__ void gload16(const unsigned short* g, unsigned short* l) {
    __builtin_amdgcn_global_load_lds(
        (__attribute__((address_space(1))) void*)g,
        (__attribute__((address_space(3))) void*)l, 16, 0, 0);
}

// ---------------- x f32 -> bf16 ----------------
__global__ __launch_bounds__(256) void k_convert(const float* __restrict__ x,
                                                 unsigned short* __restrict__ xb) {
    size_t i = ((size_t)blockIdx.x * 256 + threadIdx.x) * 8;
    f4 a = *(const f4*)(x + i);
    f4 b = *(const f4*)(x + i + 4);
    ushort8 o;
    o[0] = f2bf(a[0]); o[1] = f2bf(a[1]); o[2] = f2bf(a[2]); o[3] = f2bf(a[3]);
    o[4] = f2bf(b[0]); o[5] = f2bf(b[1]); o[6] = f2bf(b[2]); o[7] = f2bf(b[3]);
    *(ushort8*)(xb + i) = o;
}

// ---------------- W f32 -> bf16 transposed (Wt[n][k] = W[k][n]) ----------------
__global__ __launch_bounds__(256) void k_transw(const float* W0, const float* W1,
                                                const float* W2, const float* W3,
                                                unsigned short* T0, unsigned short* T1,
                                                unsigned short* T2, unsigned short* T3) {
    const float* W; unsigned short* T;
    switch (blockIdx.z) {
        case 0: W = W0; T = T0; break;
        case 1: W = W1; T = T1; break;
        case 2: W = W2; T = T2; break;
        default: W = W3; T = T3; break;
    }
    __shared__ float tile[32][33];
    int tx = threadIdx.x, ty = threadIdx.y;
    int bx = blockIdx.x * 32, by = blockIdx.y * 32;
#pragma unroll
    for (int i = 0; i < 4; i++)
        tile[ty + i * 8][tx] = W[(size_t)(by + ty + i * 8) * E_DIM + bx + tx];
    __syncthreads();
#pragma unroll
    for (int i = 0; i < 4; i++)
        T[(size_t)(bx + ty + i * 8) * E_DIM + by + tx] = f2bf(tile[tx][ty + i * 8]);
}

// ---------------- RoPE cos/sin table: [2048][32] ----------------
__global__ __launch_bounds__(256) void k_rope_table(float* __restrict__ cosT,
                                                    float* __restrict__ sinT) {
    int idx = blockIdx.x * 256 + threadIdx.x;
    int s = idx >> 5, j = idx & 31;
    float inv = expf(-(float)j * (9.210340371976184f / 32.f));
    float ang = (float)s * inv;
    cosT[idx] = cosf(ang);
    sinT[idx] = sinf(ang);
}

// ---------------- bf16 GEMM, ring-3 deep pipeline (T3/T4, 2-tile-ahead) ----------
// C = A * B^T. BK=32, 3 LDS buffers, prefetch t+2, vmcnt(8) waits loads issued
// two iterations earlier. Raw s_barrier; prefetch never drained in main loop.
// QKV3: B = [Wq;Wk;Wv] -> writes RoPE'd Q (scaled), RoPE'd K, V transposed.
template <int BM, int BN, int WGM, int WGN, int NBN, bool QKV3>
__global__ __launch_bounds__(WGM * WGN * 64, 2)
void k_gemm3(const unsigned short* __restrict__ A,
             const unsigned short* __restrict__ B,
             unsigned short* __restrict__ Qo,
             unsigned short* __restrict__ Ko,
             unsigned short* __restrict__ Vto,
             float* __restrict__ Fo,
             const float* __restrict__ cosT,
             const float* __restrict__ sinT) {
    constexpr int THREADS = WGM * WGN * 64;
    constexpr int WM = BM / WGM, WN = BN / WGN;
    constexpr int FM = WM / 16, FN = WN / 16;
    constexpr int NT = E_DIM / 32;           // 32 K-tiles of BK=32
    constexpr int RA = BM * 4 / THREADS;     // stage rounds for A (chunks of 8 elem)
    constexpr int RB = BN * 4 / THREADS;
    constexpr int MB = 4096 / BM;
    constexpr int NWG = MB * NBN;
    __shared__ unsigned short Al[3][BM * 32];
    __shared__ unsigned short Bl[3][BN * 32];
    int tid = threadIdx.x, lane = tid & 63, wid = tid >> 6;
    int l15 = lane & 15, lg = lane >> 4;
    int wr = wid / WGN, wc = wid % WGN;
    int orig = blockIdx.y * NBN + blockIdx.x;
    int wg = (orig & 7) * (NWG / 8) + (orig >> 3);   // bijective XCD swizzle
    int bm = wg / NBN, bn = wg % NBN;

    auto stage = [&](int t) {
        int buf = t % 3;
        int k0 = t * 32;
#pragma unroll
        for (int i = 0; i < RA; i++) {
            int r = i * (THREADS / 4) + wid * 16 + (lane >> 2);
            int cs = (lane & 3) ^ (r & 3);
            gload16(A + (size_t)(bm * BM + r) * E_DIM + k0 + cs * 8,
                    &Al[buf][i * (THREADS * 8) + wid * 512]);
        }
#pragma unroll
        for (int i = 0; i < RB; i++) {
            int r = i * (THREADS / 4) + wid * 16 + (lane >> 2);
            int cs = (lane & 3) ^ (r & 3);
            gload16(B + (size_t)(bn * BN + r) * E_DIM + k0 + cs * 8,
                    &Bl[buf][i * (THREADS * 8) + wid * 512]);
        }
    };

    f32x4 acc[FM][FN] = {};
    stage(0);
    stage(1);
    for (int t = 0; t < NT; t++) {
        int cur = t % 3;
        if (t + 2 < NT) {
            stage(t + 2);
            asm volatile("s_waitcnt vmcnt(8)" ::: "memory");   // tile t landed
        } else if (t + 1 < NT) {
            asm volatile("s_waitcnt vmcnt(4)" ::: "memory");
        } else {
            asm volatile("s_waitcnt vmcnt(0)" ::: "memory");
        }
        __builtin_amdgcn_s_barrier();          // all waves: tile t in LDS
        __builtin_amdgcn_sched_barrier(0);
        short8 af[FM], bfv[FN];
#pragma unroll
        for (int m = 0; m < FM; m++) {
            int r = wr * WM + m * 16 + l15;
            af[m] = *(const short8*)&Al[cur][r * 32 + ((lg ^ (r & 3)) << 3)];
        }
#pragma unroll
        for (int n = 0; n < FN; n++) {
            int r = wc * WN + n * 16 + l15;
            bfv[n] = *(const short8*)&Bl[cur][r * 32 + ((lg ^ (r & 3)) << 3)];
        }
        __builtin_amdgcn_s_setprio(1);
#pragma unroll
        for (int m = 0; m < FM; m++)
#pragma unroll
            for (int n = 0; n < FN; n++)
                acc[m][n] = __builtin_amdgcn_mfma_f32_16x16x32_bf16(
                    af[m], bfv[n], acc[m][n], 0, 0, 0);
        __builtin_amdgcn_s_setprio(0);
        __builtin_amdgcn_s_barrier();          // all waves done reading tile t
    }
    // epilogue
#pragma unroll
    for (int m = 0; m < FM; m++) {
        int r0 = bm * BM + wr * WM + m * 16 + lg * 4;
#pragma unroll
        for (int n = 0; n < FN; n++) {
            int colg = bn * BN + wc * WN + n * 16 + l15;
            if (QKV3) {
                int z = colg >> 10, c1 = colg & 1023;
                if (z == 2) {
                    int h = c1 >> 6, d = c1 & 63;
                    int bb = r0 >> 11, s = r0 & 2047;
                    ushort4_t p;
#pragma unroll
                    for (int r = 0; r < 4; r++) p[r] = f2bf(acc[m][n][r]);
                    *(ushort4_t*)(Vto + (((size_t)((bb * 16 + h) * 64 + d)) << 11) + s) = p;
                } else {
                    // fused interleaved RoPE (+ Q scale)
                    unsigned short* T = z ? Ko : Qo;
                    int dl = c1 & 63, j = dl >> 1;
                    float sgn = (dl & 1) ? 1.f : -1.f;
                    float sc = z ? 1.f : ATTN_SCALE;
#pragma unroll
                    for (int r = 0; r < 4; r++) {
                        int row = r0 + r, s = row & 2047;
                        float c = cosT[s * 32 + j], sn = sinT[s * 32 + j];
                        float v = acc[m][n][r];
                        float p = __shfl_xor(v, 1);
                        T[(size_t)row * E_DIM + c1] = f2bf((v * c + sgn * p * sn) * sc);
                    }
                }
            } else {
#pragma unroll
                for (int r = 0; r < 4; r++)
                    Fo[(size_t)(r0 + r) * E_DIM + colg] = acc[m][n][r];
            }
        }
    }
}

// ---------------- causal flash attention, bf16, counted-vmcnt pipeline ----------
// (unchanged from round 4)
__global__ __launch_bounds__(256, 2) void k_attn(const unsigned short* __restrict__ Q,
                                                 const unsigned short* __restrict__ K,
                                                 const unsigned short* __restrict__ Vt,
                                                 unsigned short* __restrict__ O) {
    __shared__ unsigned short K_lds[128 * 64];
    __shared__ unsigned short V_lds[64 * 128];
    __shared__ unsigned short P_lds[4][16][136];
    int tid = threadIdx.x, lane = tid & 63, wid = tid >> 6;
    int l15 = lane & 15, lg = lane >> 4;
    int orig = blockIdx.y * 16 + blockIdx.x;         // 512 wgs
    int wg = (orig & 7) * 64 + (orig >> 3);          // XCD swizzle
    int jp = wg & 15, bh = wg >> 4;
    int b = bh >> 4, h = bh & 15;
    const size_t base_qk = (size_t)b * S_LEN * E_DIM + (size_t)h * HD;
    const unsigned short* Vbh = Vt + ((size_t)(bh * 64) << 11);

    auto stageK = [&](int kt) {
        const unsigned short* Kb = K + base_qk + (size_t)(kt * KVB) * E_DIM;
#pragma unroll
        for (int i = 0; i < 4; i++) {
            int r = i * 32 + wid * 8 + (lane >> 3);
            int cs = (lane & 7) ^ (r & 7);
            gload16(Kb + (size_t)r * E_DIM + cs * 8, K_lds + i * 2048 + wid * 512);
        }
    };
    auto stageV = [&](int kt) {
#pragma unroll
        for (int i = 0; i < 4; i++) {
            int r = i * 16 + wid * 4 + (lane >> 4);
            int cs = (lane & 15) ^ (r & 7);
            gload16(Vbh + (size_t)r * 2048 + kt * KVB + cs * 8,
                    V_lds + i * 2048 + wid * 512);
        }
    };

    for (int pass = 0; pass < 2; ++pass) {
        int qt = pass ? (31 - jp) : jp;
        const unsigned short* Qb = Q + base_qk + (size_t)(qt * 64 + wid * 16) * E_DIM;
        short8 bq[2];
#pragma unroll
        for (int s2 = 0; s2 < 2; s2++)
            bq[s2] = *(const short8*)(Qb + (size_t)l15 * E_DIM + s2 * 32 + lg * 8);
        f32x4 acc_o[4] = {};
        float m_i = -1e30f, l_i = 0.f;
        int q_glob = qt * 64 + wid * 16 + l15;
        int nkt = (qt + 2) >> 1;
        stageK(0);
        stageV(0);
        asm volatile("s_waitcnt vmcnt(4)" ::: "memory");   // own K0 (and bq) done
        __builtin_amdgcn_s_barrier();                      // all waves' K0 landed
        __builtin_amdgcn_sched_barrier(0);
        for (int kt = 0; kt < nkt; ++kt) {
            // S^T = K . Q^T (scale pre-folded into Q)
            f32x4 acc_s[8] = {};
            __builtin_amdgcn_s_setprio(1);
#pragma unroll
            for (int mf = 0; mf < 8; mf++) {
                int rK = mf * 16 + l15;
#pragma unroll
                for (int s2 = 0; s2 < 2; s2++) {
                    int gc = s2 * 4 + lg;
                    short8 a = *(const short8*)&K_lds[rK * 64 + ((gc ^ (rK & 7)) << 3)];
                    acc_s[mf] = __builtin_amdgcn_mfma_f32_16x16x32_bf16(
                        a, bq[s2], acc_s[mf], 0, 0, 0);
                }
            }
            __builtin_amdgcn_s_setprio(0);
            __builtin_amdgcn_s_barrier();       // B1: K_lds free
            if (kt + 1 < nkt) stageK(kt + 1);
            float sv[32];
            float vmax = -1e30f;
            if (kt == nkt - 1) {
#pragma unroll
                for (int mf = 0; mf < 8; mf++)
#pragma unroll
                    for (int r = 0; r < 4; r++) {
                        int kg = kt * KVB + mf * 16 + lg * 4 + r;
                        float v = acc_s[mf][r];
                        if (kg > q_glob) v = -1e30f;
                        sv[mf * 4 + r] = v;
                        vmax = fmaxf(vmax, v);
                    }
            } else {
#pragma unroll
                for (int mf = 0; mf < 8; mf++)
#pragma unroll
                    for (int r = 0; r < 4; r++) {
                        float v = acc_s[mf][r];
                        sv[mf * 4 + r] = v;
                        vmax = fmaxf(vmax, v);
                    }
            }
            vmax = fmaxf(vmax, __shfl_xor(vmax, 16));
            vmax = fmaxf(vmax, __shfl_xor(vmax, 32));
            float m_new = fmaxf(m_i, vmax);
            float corr = __expf(m_i - m_new);
            float rowsum = 0.f;
#pragma unroll
            for (int i = 0; i < 32; i++) {
                float p = __expf(sv[i] - m_new);
                sv[i] = p;
                rowsum += p;
            }
            rowsum += __shfl_xor(rowsum, 16);
            rowsum += __shfl_xor(rowsum, 32);
            l_i = l_i * corr + rowsum;
            m_i = m_new;
            // P -> per-wave LDS [q][k] (wave-private)
#pragma unroll
            for (int mf = 0; mf < 8; mf++) {
                ushort4_t pk;
#pragma unroll
                for (int r = 0; r < 4; r++) pk[r] = f2bf(sv[mf * 4 + r]);
                *(ushort4_t*)&P_lds[wid][l15][mf * 16 + lg * 4] = pk;
            }
            // rescale O accumulator (rows at lg*4+r; corr lives at lane q)
#pragma unroll
            for (int r = 0; r < 4; r++) {
                float c4 = __shfl(corr, lg * 4 + r);
#pragma unroll
                for (int nf = 0; nf < 4; nf++) acc_o[nf][r] *= c4;
            }
            if (kt + 1 < nkt)
                asm volatile("s_waitcnt vmcnt(4)" ::: "memory");  // own V(kt) done
            else
                asm volatile("s_waitcnt vmcnt(0)" ::: "memory");
            __builtin_amdgcn_s_barrier();       // B2: all V(kt) landed
            __builtin_amdgcn_sched_barrier(0);
            // PV: O += P . V
            __builtin_amdgcn_s_setprio(1);
#pragma unroll
            for (int s2 = 0; s2 < 4; s2++) {
                short8 pa = *(const short8*)&P_lds[wid][l15][s2 * 32 + lg * 8];
#pragma unroll
                for (int nf = 0; nf < 4; nf++) {
                    int rV = nf * 16 + l15;
                    int gc = s2 * 4 + lg;
                    short8 bv = *(const short8*)&V_lds[rV * 128 + ((gc ^ (rV & 7)) << 3)];
                    acc_o[nf] = __builtin_amdgcn_mfma_f32_16x16x32_bf16(
                        pa, bv, acc_o[nf], 0, 0, 0);
                }
            }
            __builtin_amdgcn_s_setprio(0);
            __builtin_amdgcn_s_barrier();       // B3: V_lds free
            if (kt + 1 < nkt) {
                stageV(kt + 1);
                asm volatile("s_waitcnt vmcnt(4)" ::: "memory");  // own K(kt+1) done
            }
            __builtin_amdgcn_s_barrier();       // B4: all K(kt+1) landed
            __builtin_amdgcn_sched_barrier(0);
        }
        unsigned short* Ob = O + base_qk + (size_t)(qt * 64 + wid * 16) * E_DIM;
#pragma unroll
        for (int r = 0; r < 4; r++) {
            float linv = 1.f / __shfl(l_i, lg * 4 + r);
#pragma unroll
            for (int nf = 0; nf < 4; nf++)
                Ob[(size_t)(lg * 4 + r) * E_DIM + nf * 16 + l15] =
                    f2bf(acc_o[nf][r] * linv);
        }
    }
}

extern "C" void kernel_launch(void* const* d_in, const int* in_sizes, int n_in,
                              void* d_out, int out_size, void* d_ws, size_t ws_size,
                              hipStream_t stream) {
    (void)in_sizes; (void)n_in; (void)out_size; (void)ws_size;
    const float* x  = (const float*)d_in[0];
    const float* Wq = (const float*)d_in[1];
    const float* Wk = (const float*)d_in[2];
    const float* Wv = (const float*)d_in[3];
    const float* Wo = (const float*)d_in[4];

    unsigned short* us = (unsigned short*)d_ws;
    unsigned short* xb    = us;                  // 4096x1024
    unsigned short* WqkvT = us + 4194304;        // 3072x1024 (Wq;Wk;Wv rows)
    unsigned short* WoT   = us + 7340032;        // 1024x1024
    unsigned short* Qb    = us + 8388608;        // 4096x1024 (roped+scaled)
    unsigned short* Kb    = us + 12582912;       // 4096x1024 (roped)
    unsigned short* Vt    = us + 16777216;       // [b][h][d][s] = [2][16][64][2048]
    unsigned short* AO    = us + 20971520;
    float* cosT = (float*)((char*)d_ws + 50331648);
    float* sinT = cosT + 65536;

    k_convert<<<2048, 256, 0, stream>>>(x, xb);
    k_transw<<<dim3(32, 32, 4), dim3(32, 8), 0, stream>>>(
        Wq, Wk, Wv, Wo, WqkvT, WqkvT + 1048576, WqkvT + 2097152, WoT);
    k_rope_table<<<256, 256, 0, stream>>>(cosT, sinT);
    k_gemm3<256, 256, 2, 4, 12, true><<<dim3(12, 16), 512, 0, stream>>>(
        xb, WqkvT, Qb, Kb, Vt, nullptr, cosT, sinT);
    k_attn<<<dim3(16, 32), 256, 0, stream>>>(Qb, Kb, Vt, AO);
    k_gemm3<128, 128, 2, 2, 8, false><<<dim3(8, 32), 256, 0, stream>>>(
        AO, WoT, nullptr, nullptr, nullptr, (float*)d_out, cosT, sinT);
}

// Round 6
// 118.003 us; speedup vs baseline: 1.1245x; 1.1245x over previous
//
#include <hip/hip_runtime.h>
#include <hip/hip_bf16.h>

#define S_LEN 2048
#define E_DIM 1024
#define NH 16
#define HD 64
#define ATTN_SCALE 0.03125f   // 1/sqrt(1024)
#define KVB 128

typedef __attribute__((ext_vector_type(8))) short short8;
typedef __attribute__((ext_vector_type(8))) unsigned short ushort8;
typedef __attribute__((ext_vector_type(4))) unsigned short ushort4_t;
typedef __attribute__((ext_vector_type(4))) float f32x4;
typedef __attribute__((ext_vector_type(4))) float f4;

__device__ __forceinline__ float bf2f(unsigned short u) {
    unsigned int x = ((unsigned int)u) << 16;
    return __builtin_bit_cast(float, x);
}
__device__ __forceinline__ unsigned short f2bf(float f) {
    unsigned int x = __builtin_bit_cast(unsigned int, f);
    x += 0x7FFFu + ((x >> 16) & 1u);   // RNE
    return (unsigned short)(x >> 16);
}
__device__ __forceinline__ void gload16(const unsigned short* g, unsigned short* l) {
    __builtin_amdgcn_global_load_lds(
        (__attribute__((address_space(1))) void*)g,
        (__attribute__((address_space(3))) void*)l, 16, 0, 0);
}

// ---------------- x f32 -> bf16 ----------------
__global__ __launch_bounds__(256) void k_convert(const float* __restrict__ x,
                                                 unsigned short* __restrict__ xb) {
    size_t i = ((size_t)blockIdx.x * 256 + threadIdx.x) * 8;
    f4 a = *(const f4*)(x + i);
    f4 b = *(const f4*)(x + i + 4);
    ushort8 o;
    o[0] = f2bf(a[0]); o[1] = f2bf(a[1]); o[2] = f2bf(a[2]); o[3] = f2bf(a[3]);
    o[4] = f2bf(b[0]); o[5] = f2bf(b[1]); o[6] = f2bf(b[2]); o[7] = f2bf(b[3]);
    *(ushort8*)(xb + i) = o;
}

// ---------------- W f32 -> bf16 transposed (Wt[n][k] = W[k][n]) ----------------
__global__ __launch_bounds__(256) void k_transw(const float* W0, const float* W1,
                                                const float* W2, const float* W3,
                                                unsigned short* T0, unsigned short* T1,
                                                unsigned short* T2, unsigned short* T3) {
    const float* W; unsigned short* T;
    switch (blockIdx.z) {
        case 0: W = W0; T = T0; break;
        case 1: W = W1; T = T1; break;
        case 2: W = W2; T = T2; break;
        default: W = W3; T = T3; break;
    }
    __shared__ float tile[32][33];
    int tx = threadIdx.x, ty = threadIdx.y;
    int bx = blockIdx.x * 32, by = blockIdx.y * 32;
#pragma unroll
    for (int i = 0; i < 4; i++)
        tile[ty + i * 8][tx] = W[(size_t)(by + ty + i * 8) * E_DIM + bx + tx];
    __syncthreads();
#pragma unroll
    for (int i = 0; i < 4; i++)
        T[(size_t)(bx + ty + i * 8) * E_DIM + by + tx] = f2bf(tile[tx][ty + i * 8]);
}

// ---------------- RoPE cos/sin table: [2048][32] ----------------
__global__ __launch_bounds__(256) void k_rope_table(float* __restrict__ cosT,
                                                    float* __restrict__ sinT) {
    int idx = blockIdx.x * 256 + threadIdx.x;
    int s = idx >> 5, j = idx & 31;
    float inv = expf(-(float)j * (9.210340371976184f / 32.f));
    float ang = (float)s * inv;
    cosT[idx] = cosf(ang);
    sinT[idx] = sinf(ang);
}

// ---------------- QKV GEMM: 256x256 tile, 8-phase interleave (T2+T3+T4+T5) ------
// C = A * B^T, A [4096][1024] bf16, B = [Wq;Wk;Wv] [3072][1024] bf16.
// 8 waves (2M x 4N), per-wave out 128x64. BK=64, 4 phases/K-tile (C-quadrants).
// LDS: 2 buf x (A 2 halves + B 2 halves) x 16KB = 128KB.
// Stage: A(kt+1) at phases 1,2; B(kt+2) at phases 3,4 (B region dead after ph2).
// Single vmcnt(4) per K-tile at phase 4. Epilogue: fused RoPE(Q,K) + Vt scatter.
__global__ __launch_bounds__(512, 2)
void k_gemm8(const unsigned short* __restrict__ A,
             const unsigned short* __restrict__ B,
             unsigned short* __restrict__ Qo,
             unsigned short* __restrict__ Ko,
             unsigned short* __restrict__ Vto,
             const float* __restrict__ cosT,
             const float* __restrict__ sinT) {
    constexpr int NT = 16;       // K-tiles of 64
    constexpr int NBN = 12;      // 3072/256
    __shared__ unsigned short Al[2][2][8192];   // [buf][half][128*64]
    __shared__ unsigned short Bl[2][2][8192];
    int tid = threadIdx.x, lane = tid & 63, wid = tid >> 6;
    int l15 = lane & 15, lg = lane >> 4;
    int wr = wid >> 2, wc = wid & 3;
    int orig = blockIdx.y * NBN + blockIdx.x;        // 0..191
    int wg = (orig & 7) * 24 + (orig >> 3);          // bijective XCD swizzle (192%8==0)
    int bm = wg / NBN, bn = wg % NBN;
    int sr = tid >> 3, sc = tid & 7;                 // stage row/chunk
    const unsigned short* Abase = A + (size_t)(bm * 256) * E_DIM;
    const unsigned short* Bbase = B + (size_t)(bn * 256) * E_DIM;

    auto stageA = [&](int buf, int half, int kt) {
#pragma unroll
        for (int i = 0; i < 2; i++) {
            int r = i * 64 + sr;
            int cs = sc ^ (r & 7);
            gload16(Abase + (size_t)(half * 128 + r) * E_DIM + kt * 64 + cs * 8,
                    &Al[buf][half][i * 4096 + tid * 8]);
        }
    };
    auto stageB = [&](int buf, int half, int kt) {
#pragma unroll
        for (int i = 0; i < 2; i++) {
            int r = i * 64 + sr;
            int cs = sc ^ (r & 7);
            gload16(Bbase + (size_t)(half * 128 + r) * E_DIM + kt * 64 + cs * 8,
                    &Bl[buf][half][i * 4096 + tid * 8]);
        }
    };

    f32x4 acc[8][4] = {};
    short8 af[8], bf0[4], bf1[4];
    int swz = l15 & 7;   // row&7 for all fragment rows this lane reads

    auto ldsA = [&](int cur, int mh) {    // 8 x ds_read_b128
#pragma unroll
        for (int j = 0; j < 4; j++)
#pragma unroll
            for (int ks = 0; ks < 2; ks++)
                af[j * 2 + ks] = *(const short8*)
                    &Al[cur][wr][(mh * 64 + j * 16 + l15) * 64 +
                                 (((ks * 4 + lg) ^ swz) << 3)];
    };
    auto ldsB = [&](int cur, int nh, short8* bf) {   // 4 x ds_read_b128
#pragma unroll
        for (int n = 0; n < 2; n++)
#pragma unroll
            for (int ks = 0; ks < 2; ks++)
                bf[n * 2 + ks] = *(const short8*)
                    &Bl[cur][wc >> 1][((wc & 1) * 64 + (nh * 2 + n) * 16 + l15) * 64 +
                                      (((ks * 4 + lg) ^ swz) << 3)];
    };
    auto mma = [&](int mh, int nh, short8* bf) {     // 16 MFMA (one quadrant)
        __builtin_amdgcn_s_setprio(1);
#pragma unroll
        for (int j = 0; j < 4; j++)
#pragma unroll
            for (int n = 0; n < 2; n++)
#pragma unroll
                for (int ks = 0; ks < 2; ks++)
                    acc[mh * 4 + j][nh * 2 + n] = __builtin_amdgcn_mfma_f32_16x16x32_bf16(
                        af[j * 2 + ks], bf[n * 2 + ks], acc[mh * 4 + j][nh * 2 + n], 0, 0, 0);
        __builtin_amdgcn_s_setprio(0);
    };

    // prologue: A(0),B(0) into buf0; B(1) into buf1
    stageA(0, 0, 0); stageA(0, 1, 0);
    stageB(0, 0, 0); stageB(0, 1, 0);
    stageB(1, 0, 1); stageB(1, 1, 1);
    asm volatile("s_waitcnt vmcnt(4)" ::: "memory");   // A(0),B(0) landed
    __builtin_amdgcn_s_barrier();
    __builtin_amdgcn_sched_barrier(0);

    for (int kt = 0; kt < NT; kt++) {
        int cur = kt & 1;
        int ka = kt + 1 < NT ? kt + 1 : NT - 1;
        int kb = kt + 2 < NT ? kt + 2 : NT - 1;
        // ---- phase 1: quadrant (mh0, nh0) ----
        ldsA(cur, 0);
        ldsB(cur, 0, bf0);
        stageA(cur ^ 1, 0, ka);
        asm volatile("s_waitcnt lgkmcnt(8)" ::: "memory");
        __builtin_amdgcn_s_barrier();
        asm volatile("s_waitcnt lgkmcnt(0)" ::: "memory");
        __builtin_amdgcn_sched_barrier(0);
        mma(0, 0, bf0);
        __builtin_amdgcn_s_barrier();
        // ---- phase 2: quadrant (mh0, nh1) ----
        ldsB(cur, 1, bf1);
        stageA(cur ^ 1, 1, ka);
        __builtin_amdgcn_s_barrier();
        asm volatile("s_waitcnt lgkmcnt(0)" ::: "memory");
        __builtin_amdgcn_sched_barrier(0);
        mma(0, 1, bf1);
        __builtin_amdgcn_s_barrier();          // after this, B(cur) LDS is dead
        // ---- phase 3: quadrant (mh1, nh1) ----
        ldsA(cur, 1);
        stageB(cur, 0, kb);                    // overwrite dead B region
        __builtin_amdgcn_s_barrier();
        asm volatile("s_waitcnt lgkmcnt(0)" ::: "memory");
        __builtin_amdgcn_sched_barrier(0);
        mma(1, 1, bf1);
        __builtin_amdgcn_s_barrier();
        // ---- phase 4: quadrant (mh1, nh0) ----
        stageB(cur, 1, kb);
        asm volatile("s_waitcnt vmcnt(4)" ::: "memory");  // A(kt+1),B(kt+1) landed
        __builtin_amdgcn_s_barrier();
        __builtin_amdgcn_sched_barrier(0);
        mma(1, 0, bf0);
        __builtin_amdgcn_s_barrier();
    }

    // epilogue: fused RoPE for Q/K columns, transposed scatter for V columns
#pragma unroll
    for (int m = 0; m < 8; m++) {
        int r0 = bm * 256 + wr * 128 + m * 16 + lg * 4;
#pragma unroll
        for (int n = 0; n < 4; n++) {
            int colg = bn * 256 + wc * 64 + n * 16 + l15;
            int z = colg >> 10, c1 = colg & 1023;
            if (z == 2) {
                int h = c1 >> 6, d = c1 & 63;
                int bb = r0 >> 11, s = r0 & 2047;
                ushort4_t p;
#pragma unroll
                for (int r = 0; r < 4; r++) p[r] = f2bf(acc[m][n][r]);
                *(ushort4_t*)(Vto + (((size_t)((bb * 16 + h) * 64 + d)) << 11) + s) = p;
            } else {
                unsigned short* T = z ? Ko : Qo;
                int dl = c1 & 63, j = dl >> 1;
                float sgn = (dl & 1) ? 1.f : -1.f;
                float scq = z ? 1.f : ATTN_SCALE;
#pragma unroll
                for (int r = 0; r < 4; r++) {
                    int row = r0 + r, s = row & 2047;
                    float c = cosT[s * 32 + j], sn = sinT[s * 32 + j];
                    float v = acc[m][n][r];
                    float p = __shfl_xor(v, 1);
                    T[(size_t)row * E_DIM + c1] = f2bf((v * c + sgn * p * sn) * scq);
                }
            }
        }
    }
}

// ---------------- out-proj GEMM (R4 counted-vmcnt 2-phase) ----------------
template <int BM, int BN, int WGM, int WGN, int NBN>
__global__ __launch_bounds__(WGM * WGN * 64, 2)
void k_gemmo(const unsigned short* __restrict__ A,
             const unsigned short* __restrict__ B,
             float* __restrict__ Fo) {
    constexpr int THREADS = WGM * WGN * 64;
    constexpr int WM = BM / WGM, WN = BN / WGN;
    constexpr int FM = WM / 16, FN = WN / 16;
    constexpr int NT = E_DIM / 64;
    constexpr int AR = BM * 8 / THREADS;
    constexpr int BR = BN * 8 / THREADS;
    constexpr int STG = AR + BR;
    constexpr int NWG = (4096 / BM) * NBN;
    __shared__ unsigned short Al[2][BM * 64];
    __shared__ unsigned short Bl[2][BN * 64];
    int tid = threadIdx.x, lane = tid & 63, wid = tid >> 6;
    int l15 = lane & 15, lg = lane >> 4;
    int wr = wid / WGN, wc = wid % WGN;
    int orig = blockIdx.y * NBN + blockIdx.x;
    int wg = (orig & 7) * (NWG / 8) + (orig >> 3);
    int bm = wg / NBN, bn = wg % NBN;

    auto stage = [&](int buf, int k0) {
#pragma unroll
        for (int i = 0; i < AR; i++) {
            int r = i * (THREADS / 8) + wid * 8 + (lane >> 3);
            int cs = (lane & 7) ^ (r & 7);
            gload16(A + (size_t)(bm * BM + r) * E_DIM + k0 + cs * 8,
                    &Al[buf][i * (THREADS * 8) + wid * 512]);
        }
#pragma unroll
        for (int i = 0; i < BR; i++) {
            int r = i * (THREADS / 8) + wid * 8 + (lane >> 3);
            int cs = (lane & 7) ^ (r & 7);
            gload16(B + (size_t)(bn * BN + r) * E_DIM + k0 + cs * 8,
                    &Bl[buf][i * (THREADS * 8) + wid * 512]);
        }
    };

    f32x4 acc[FM][FN] = {};
    stage(0, 0);
    for (int t = 0; t < NT; t++) {
        int cur = t & 1;
        if (t + 1 < NT) {
            stage(cur ^ 1, (t + 1) * 64);
            asm volatile("s_waitcnt vmcnt(%0)" :: "n"(STG) : "memory");
        } else {
            asm volatile("s_waitcnt vmcnt(0)" ::: "memory");
        }
        __builtin_amdgcn_s_barrier();
        __builtin_amdgcn_sched_barrier(0);
#pragma unroll
        for (int ks = 0; ks < 2; ks++) {
            short8 af[FM], bfv[FN];
#pragma unroll
            for (int m = 0; m < FM; m++) {
                int r = wr * WM + m * 16 + l15;
                int gc = ks * 4 + lg;
                af[m] = *(const short8*)&Al[cur][r * 64 + ((gc ^ (r & 7)) << 3)];
            }
#pragma unroll
            for (int n = 0; n < FN; n++) {
                int r = wc * WN + n * 16 + l15;
                int gc = ks * 4 + lg;
                bfv[n] = *(const short8*)&Bl[cur][r * 64 + ((gc ^ (r & 7)) << 3)];
            }
#pragma unroll
            for (int m = 0; m < FM; m++)
#pragma unroll
                for (int n = 0; n < FN; n++)
                    acc[m][n] = __builtin_amdgcn_mfma_f32_16x16x32_bf16(
                        af[m], bfv[n], acc[m][n], 0, 0, 0);
        }
        __builtin_amdgcn_s_barrier();
    }
#pragma unroll
    for (int m = 0; m < FM; m++) {
        int r0 = bm * BM + wr * WM + m * 16 + lg * 4;
#pragma unroll
        for (int n = 0; n < FN; n++) {
            int colg = bn * BN + wc * WN + n * 16 + l15;
#pragma unroll
            for (int r = 0; r < 4; r++)
                Fo[(size_t)(r0 + r) * E_DIM + colg] = acc[m][n][r];
        }
    }
}

// ---------------- causal flash attention, bf16, counted-vmcnt pipeline ----------
// (unchanged from round 4)
__global__ __launch_bounds__(256, 2) void k_attn(const unsigned short* __restrict__ Q,
                                                 const unsigned short* __restrict__ K,
                                                 const unsigned short* __restrict__ Vt,
                                                 unsigned short* __restrict__ O) {
    __shared__ unsigned short K_lds[128 * 64];
    __shared__ unsigned short V_lds[64 * 128];
    __shared__ unsigned short P_lds[4][16][136];
    int tid = threadIdx.x, lane = tid & 63, wid = tid >> 6;
    int l15 = lane & 15, lg = lane >> 4;
    int orig = blockIdx.y * 16 + blockIdx.x;         // 512 wgs
    int wg = (orig & 7) * 64 + (orig >> 3);          // XCD swizzle
    int jp = wg & 15, bh = wg >> 4;
    int b = bh >> 4, h = bh & 15;
    const size_t base_qk = (size_t)b * S_LEN * E_DIM + (size_t)h * HD;
    const unsigned short* Vbh = Vt + ((size_t)(bh * 64) << 11);

    auto stageK = [&](int kt) {
        const unsigned short* Kb = K + base_qk + (size_t)(kt * KVB) * E_DIM;
#pragma unroll
        for (int i = 0; i < 4; i++) {
            int r = i * 32 + wid * 8 + (lane >> 3);
            int cs = (lane & 7) ^ (r & 7);
            gload16(Kb + (size_t)r * E_DIM + cs * 8, K_lds + i * 2048 + wid * 512);
        }
    };
    auto stageV = [&](int kt) {
#pragma unroll
        for (int i = 0; i < 4; i++) {
            int r = i * 16 + wid * 4 + (lane >> 4);
            int cs = (lane & 15) ^ (r & 7);
            gload16(Vbh + (size_t)r * 2048 + kt * KVB + cs * 8,
                    V_lds + i * 2048 + wid * 512);
        }
    };

    for (int pass = 0; pass < 2; ++pass) {
        int qt = pass ? (31 - jp) : jp;
        const unsigned short* Qb = Q + base_qk + (size_t)(qt * 64 + wid * 16) * E_DIM;
        short8 bq[2];
#pragma unroll
        for (int s2 = 0; s2 < 2; s2++)
            bq[s2] = *(const short8*)(Qb + (size_t)l15 * E_DIM + s2 * 32 + lg * 8);
        f32x4 acc_o[4] = {};
        float m_i = -1e30f, l_i = 0.f;
        int q_glob = qt * 64 + wid * 16 + l15;
        int nkt = (qt + 2) >> 1;
        stageK(0);
        stageV(0);
        asm volatile("s_waitcnt vmcnt(4)" ::: "memory");   // own K0 (and bq) done
        __builtin_amdgcn_s_barrier();                      // all waves' K0 landed
        __builtin_amdgcn_sched_barrier(0);
        for (int kt = 0; kt < nkt; ++kt) {
            f32x4 acc_s[8] = {};
            __builtin_amdgcn_s_setprio(1);
#pragma unroll
            for (int mf = 0; mf < 8; mf++) {
                int rK = mf * 16 + l15;
#pragma unroll
                for (int s2 = 0; s2 < 2; s2++) {
                    int gc = s2 * 4 + lg;
                    short8 a = *(const short8*)&K_lds[rK * 64 + ((gc ^ (rK & 7)) << 3)];
                    acc_s[mf] = __builtin_amdgcn_mfma_f32_16x16x32_bf16(
                        a, bq[s2], acc_s[mf], 0, 0, 0);
                }
            }
            __builtin_amdgcn_s_setprio(0);
            __builtin_amdgcn_s_barrier();       // B1: K_lds free
            if (kt + 1 < nkt) stageK(kt + 1);
            float sv[32];
            float vmax = -1e30f;
            if (kt == nkt - 1) {
#pragma unroll
                for (int mf = 0; mf < 8; mf++)
#pragma unroll
                    for (int r = 0; r < 4; r++) {
                        int kg = kt * KVB + mf * 16 + lg * 4 + r;
                        float v = acc_s[mf][r];
                        if (kg > q_glob) v = -1e30f;
                        sv[mf * 4 + r] = v;
                        vmax = fmaxf(vmax, v);
                    }
            } else {
#pragma unroll
                for (int mf = 0; mf < 8; mf++)
#pragma unroll
                    for (int r = 0; r < 4; r++) {
                        float v = acc_s[mf][r];
                        sv[mf * 4 + r] = v;
                        vmax = fmaxf(vmax, v);
                    }
            }
            vmax = fmaxf(vmax, __shfl_xor(vmax, 16));
            vmax = fmaxf(vmax, __shfl_xor(vmax, 32));
            float m_new = fmaxf(m_i, vmax);
            float corr = __expf(m_i - m_new);
            float rowsum = 0.f;
#pragma unroll
            for (int i = 0; i < 32; i++) {
                float p = __expf(sv[i] - m_new);
                sv[i] = p;
                rowsum += p;
            }
            rowsum += __shfl_xor(rowsum, 16);
            rowsum += __shfl_xor(rowsum, 32);
            l_i = l_i * corr + rowsum;
            m_i = m_new;
#pragma unroll
            for (int mf = 0; mf < 8; mf++) {
                ushort4_t pk;
#pragma unroll
                for (int r = 0; r < 4; r++) pk[r] = f2bf(sv[mf * 4 + r]);
                *(ushort4_t*)&P_lds[wid][l15][mf * 16 + lg * 4] = pk;
            }
#pragma unroll
            for (int r = 0; r < 4; r++) {
                float c4 = __shfl(corr, lg * 4 + r);
#pragma unroll
                for (int nf = 0; nf < 4; nf++) acc_o[nf][r] *= c4;
            }
            if (kt + 1 < nkt)
                asm volatile("s_waitcnt vmcnt(4)" ::: "memory");  // own V(kt) done
            else
                asm volatile("s_waitcnt vmcnt(0)" ::: "memory");
            __builtin_amdgcn_s_barrier();       // B2: all V(kt) landed
            __builtin_amdgcn_sched_barrier(0);
            __builtin_amdgcn_s_setprio(1);
#pragma unroll
            for (int s2 = 0; s2 < 4; s2++) {
                short8 pa = *(const short8*)&P_lds[wid][l15][s2 * 32 + lg * 8];
#pragma unroll
                for (int nf = 0; nf < 4; nf++) {
                    int rV = nf * 16 + l15;
                    int gc = s2 * 4 + lg;
                    short8 bv = *(const short8*)&V_lds[rV * 128 + ((gc ^ (rV & 7)) << 3)];
                    acc_o[nf] = __builtin_amdgcn_mfma_f32_16x16x32_bf16(
                        pa, bv, acc_o[nf], 0, 0, 0);
                }
            }
            __builtin_amdgcn_s_setprio(0);
            __builtin_amdgcn_s_barrier();       // B3: V_lds free
            if (kt + 1 < nkt) {
                stageV(kt + 1);
                asm volatile("s_waitcnt vmcnt(4)" ::: "memory");  // own K(kt+1) done
            }
            __builtin_amdgcn_s_barrier();       // B4: all K(kt+1) landed
            __builtin_amdgcn_sched_barrier(0);
        }
        unsigned short* Ob = O + base_qk + (size_t)(qt * 64 + wid * 16) * E_DIM;
#pragma unroll
        for (int r = 0; r < 4; r++) {
            float linv = 1.f / __shfl(l_i, lg * 4 + r);
#pragma unroll
            for (int nf = 0; nf < 4; nf++)
                Ob[(size_t)(lg * 4 + r) * E_DIM + nf * 16 + l15] =
                    f2bf(acc_o[nf][r] * linv);
        }
    }
}

extern "C" void kernel_launch(void* const* d_in, const int* in_sizes, int n_in,
                              void* d_out, int out_size, void* d_ws, size_t ws_size,
                              hipStream_t stream) {
    (void)in_sizes; (void)n_in; (void)out_size; (void)ws_size;
    const float* x  = (const float*)d_in[0];
    const float* Wq = (const float*)d_in[1];
    const float* Wk = (const float*)d_in[2];
    const float* Wv = (const float*)d_in[3];
    const float* Wo = (const float*)d_in[4];

    unsigned short* us = (unsigned short*)d_ws;
    unsigned short* xb    = us;                  // 4096x1024
    unsigned short* WqkvT = us + 4194304;        // 3072x1024 (Wq;Wk;Wv rows)
    unsigned short* WoT   = us + 7340032;        // 1024x1024
    unsigned short* Qb    = us + 8388608;        // 4096x1024 (roped+scaled)
    unsigned short* Kb    = us + 12582912;       // 4096x1024 (roped)
    unsigned short* Vt    = us + 16777216;       // [b][h][d][s] = [2][16][64][2048]
    unsigned short* AO    = us + 20971520;
    float* cosT = (float*)((char*)d_ws + 50331648);
    float* sinT = cosT + 65536;

    k_convert<<<2048, 256, 0, stream>>>(x, xb);
    k_transw<<<dim3(32, 32, 4), dim3(32, 8), 0, stream>>>(
        Wq, Wk, Wv, Wo, WqkvT, WqkvT + 1048576, WqkvT + 2097152, WoT);
    k_rope_table<<<256, 256, 0, stream>>>(cosT, sinT);
    k_gemm8<<<dim3(12, 16), 512, 0, stream>>>(xb, WqkvT, Qb, Kb, Vt, cosT, sinT);
    k_attn<<<dim3(16, 32), 256, 0, stream>>>(Qb, Kb, Vt, AO);
    k_gemmo<128, 64, 2, 2, 16><<<dim3(16, 32), 256, 0, stream>>>(
        AO, WoT, (float*)d_out);
}

// Round 7
// 110.837 us; speedup vs baseline: 1.1972x; 1.0647x over previous
//
#include <hip/hip_runtime.h>
#include <hip/hip_bf16.h>

#define S_LEN 2048
#define E_DIM 1024
#define NH 16
#define HD 64
#define ATTN_SCALE 0.03125f   // 1/sqrt(1024)
#define KVB 128

typedef __attribute__((ext_vector_type(8))) short short8;
typedef __attribute__((ext_vector_type(8))) unsigned short ushort8;
typedef __attribute__((ext_vector_type(4))) unsigned short ushort4_t;
typedef __attribute__((ext_vector_type(4))) float f32x4;
typedef __attribute__((ext_vector_type(4))) float f4;

__device__ __forceinline__ float bf2f(unsigned short u) {
    unsigned int x = ((unsigned int)u) << 16;
    return __builtin_bit_cast(float, x);
}
__device__ __forceinline__ unsigned short f2bf(float f) {
    unsigned int x = __builtin_bit_cast(unsigned int, f);
    x += 0x7FFFu + ((x >> 16) & 1u);   // RNE
    return (unsigned short)(x >> 16);
}
__device__ __forceinline__ void gload16(const unsigned short* g, unsigned short* l) {
    __builtin_amdgcn_global_load_lds(
        (__attribute__((address_space(1))) void*)g,
        (__attribute__((address_space(3))) void*)l, 16, 0, 0);
}

// ---------------- x f32 -> bf16 ----------------
__global__ __launch_bounds__(256) void k_convert(const float* __restrict__ x,
                                                 unsigned short* __restrict__ xb) {
    size_t i = ((size_t)blockIdx.x * 256 + threadIdx.x) * 8;
    f4 a = *(const f4*)(x + i);
    f4 b = *(const f4*)(x + i + 4);
    ushort8 o;
    o[0] = f2bf(a[0]); o[1] = f2bf(a[1]); o[2] = f2bf(a[2]); o[3] = f2bf(a[3]);
    o[4] = f2bf(b[0]); o[5] = f2bf(b[1]); o[6] = f2bf(b[2]); o[7] = f2bf(b[3]);
    *(ushort8*)(xb + i) = o;
}

// ---------------- W f32 -> bf16 transposed (Wt[n][k] = W[k][n]) ----------------
__global__ __launch_bounds__(256) void k_transw(const float* W0, const float* W1,
                                                const float* W2, const float* W3,
                                                unsigned short* T0, unsigned short* T1,
                                                unsigned short* T2, unsigned short* T3) {
    const float* W; unsigned short* T;
    switch (blockIdx.z) {
        case 0: W = W0; T = T0; break;
        case 1: W = W1; T = T1; break;
        case 2: W = W2; T = T2; break;
        default: W = W3; T = T3; break;
    }
    __shared__ float tile[32][33];
    int tx = threadIdx.x, ty = threadIdx.y;
    int bx = blockIdx.x * 32, by = blockIdx.y * 32;
#pragma unroll
    for (int i = 0; i < 4; i++)
        tile[ty + i * 8][tx] = W[(size_t)(by + ty + i * 8) * E_DIM + bx + tx];
    __syncthreads();
#pragma unroll
    for (int i = 0; i < 4; i++)
        T[(size_t)(bx + ty + i * 8) * E_DIM + by + tx] = f2bf(tile[tx][ty + i * 8]);
}

// ---------------- RoPE cos/sin table: [2048][32] ----------------
__global__ __launch_bounds__(256) void k_rope_table(float* __restrict__ cosT,
                                                    float* __restrict__ sinT) {
    int idx = blockIdx.x * 256 + threadIdx.x;
    int s = idx >> 5, j = idx & 31;
    float inv = expf(-(float)j * (9.210340371976184f / 32.f));
    float ang = (float)s * inv;
    cosT[idx] = cosf(ang);
    sinT[idx] = sinf(ang);
}

// ---------------- bf16 GEMM: small-tile 2-phase counted-vmcnt, 3 wgs/CU ----------
// C = A * B^T. BM=128, BN=64, 4 waves (2x2), BK=64, dbuf LDS 48KB.
// Latency hidden by 3 co-resident wgs (m97/m114 regime), not by deep pipeline.
// QKV3: B = [Wq;Wk;Wv] -> RoPE'd Q (scaled), RoPE'd K, V transposed.
template <int BM, int BN, int NBN, bool QKV3>
__global__ __launch_bounds__(256, 3)
void k_gemmN(const unsigned short* __restrict__ A,
             const unsigned short* __restrict__ B,
             unsigned short* __restrict__ Qo,
             unsigned short* __restrict__ Ko,
             unsigned short* __restrict__ Vto,
             float* __restrict__ Fo,
             const float* __restrict__ cosT,
             const float* __restrict__ sinT) {
    constexpr int THREADS = 256;
    constexpr int WM = BM / 2, WN = BN / 2;
    constexpr int FM = WM / 16, FN = WN / 16;
    constexpr int NT = E_DIM / 64;
    constexpr int AR = BM * 8 / THREADS;     // 16B-chunk rounds for A (8 chunks/row)
    constexpr int BR = BN * 8 / THREADS;
    constexpr int STG = AR + BR;
    constexpr int NWG = (4096 / BM) * NBN;
    __shared__ unsigned short Al[2][BM * 64];
    __shared__ unsigned short Bl[2][BN * 64];
    int tid = threadIdx.x, lane = tid & 63, wid = tid >> 6;
    int l15 = lane & 15, lg = lane >> 4;
    int wr = wid >> 1, wc = wid & 1;
    int orig = blockIdx.y * NBN + blockIdx.x;
    int wg = (orig & 7) * (NWG / 8) + (orig >> 3);   // bijective XCD swizzle
    int bm = wg / NBN, bn = wg % NBN;

    auto stage = [&](int buf, int k0) {
#pragma unroll
        for (int i = 0; i < AR; i++) {
            int r = i * (THREADS / 8) + wid * 8 + (lane >> 3);
            int cs = (lane & 7) ^ (r & 7);
            gload16(A + (size_t)(bm * BM + r) * E_DIM + k0 + cs * 8,
                    &Al[buf][i * (THREADS * 8) + wid * 512]);
        }
#pragma unroll
        for (int i = 0; i < BR; i++) {
            int r = i * (THREADS / 8) + wid * 8 + (lane >> 3);
            int cs = (lane & 7) ^ (r & 7);
            gload16(B + (size_t)(bn * BN + r) * E_DIM + k0 + cs * 8,
                    &Bl[buf][i * (THREADS * 8) + wid * 512]);
        }
    };

    f32x4 acc[FM][FN] = {};
    stage(0, 0);
    for (int t = 0; t < NT; t++) {
        int cur = t & 1;
        if (t + 1 < NT) {
            stage(cur ^ 1, (t + 1) * 64);
            asm volatile("s_waitcnt vmcnt(%0)" :: "n"(STG) : "memory");
        } else {
            asm volatile("s_waitcnt vmcnt(0)" ::: "memory");
        }
        __builtin_amdgcn_s_barrier();
        __builtin_amdgcn_sched_barrier(0);
#pragma unroll
        for (int ks = 0; ks < 2; ks++) {
            short8 af[FM], bfv[FN];
#pragma unroll
            for (int m = 0; m < FM; m++) {
                int r = wr * WM + m * 16 + l15;
                int gc = ks * 4 + lg;
                af[m] = *(const short8*)&Al[cur][r * 64 + ((gc ^ (r & 7)) << 3)];
            }
#pragma unroll
            for (int n = 0; n < FN; n++) {
                int r = wc * WN + n * 16 + l15;
                int gc = ks * 4 + lg;
                bfv[n] = *(const short8*)&Bl[cur][r * 64 + ((gc ^ (r & 7)) << 3)];
            }
            __builtin_amdgcn_s_setprio(1);
#pragma unroll
            for (int m = 0; m < FM; m++)
#pragma unroll
                for (int n = 0; n < FN; n++)
                    acc[m][n] = __builtin_amdgcn_mfma_f32_16x16x32_bf16(
                        af[m], bfv[n], acc[m][n], 0, 0, 0);
            __builtin_amdgcn_s_setprio(0);
        }
        __builtin_amdgcn_s_barrier();
    }
    // epilogue
#pragma unroll
    for (int m = 0; m < FM; m++) {
        int r0 = bm * BM + wr * WM + m * 16 + lg * 4;
#pragma unroll
        for (int n = 0; n < FN; n++) {
            int colg = bn * BN + wc * WN + n * 16 + l15;
            if (QKV3) {
                int z = colg >> 10, c1 = colg & 1023;
                if (z == 2) {
                    int h = c1 >> 6, d = c1 & 63;
                    int bb = r0 >> 11, s = r0 & 2047;
                    ushort4_t p;
#pragma unroll
                    for (int r = 0; r < 4; r++) p[r] = f2bf(acc[m][n][r]);
                    *(ushort4_t*)(Vto + (((size_t)((bb * 16 + h) * 64 + d)) << 11) + s) = p;
                } else {
                    // fused interleaved RoPE (+ Q scale)
                    unsigned short* T = z ? Ko : Qo;
                    int dl = c1 & 63, j = dl >> 1;
                    float sgn = (dl & 1) ? 1.f : -1.f;
                    float scq = z ? 1.f : ATTN_SCALE;
#pragma unroll
                    for (int r = 0; r < 4; r++) {
                        int row = r0 + r, s = row & 2047;
                        float c = cosT[s * 32 + j], sn = sinT[s * 32 + j];
                        float v = acc[m][n][r];
                        float p = __shfl_xor(v, 1);
                        T[(size_t)row * E_DIM + c1] = f2bf((v * c + sgn * p * sn) * scq);
                    }
                }
            } else {
#pragma unroll
                for (int r = 0; r < 4; r++)
                    Fo[(size_t)(r0 + r) * E_DIM + colg] = acc[m][n][r];
            }
        }
    }
}

// ---------------- causal flash attention, bf16, counted-vmcnt pipeline ----------
// (unchanged from round 4)
__global__ __launch_bounds__(256, 2) void k_attn(const unsigned short* __restrict__ Q,
                                                 const unsigned short* __restrict__ K,
                                                 const unsigned short* __restrict__ Vt,
                                                 unsigned short* __restrict__ O) {
    __shared__ unsigned short K_lds[128 * 64];
    __shared__ unsigned short V_lds[64 * 128];
    __shared__ unsigned short P_lds[4][16][136];
    int tid = threadIdx.x, lane = tid & 63, wid = tid >> 6;
    int l15 = lane & 15, lg = lane >> 4;
    int orig = blockIdx.y * 16 + blockIdx.x;         // 512 wgs
    int wg = (orig & 7) * 64 + (orig >> 3);          // XCD swizzle
    int jp = wg & 15, bh = wg >> 4;
    int b = bh >> 4, h = bh & 15;
    const size_t base_qk = (size_t)b * S_LEN * E_DIM + (size_t)h * HD;
    const unsigned short* Vbh = Vt + ((size_t)(bh * 64) << 11);

    auto stageK = [&](int kt) {
        const unsigned short* Kb = K + base_qk + (size_t)(kt * KVB) * E_DIM;
#pragma unroll
        for (int i = 0; i < 4; i++) {
            int r = i * 32 + wid * 8 + (lane >> 3);
            int cs = (lane & 7) ^ (r & 7);
            gload16(Kb + (size_t)r * E_DIM + cs * 8, K_lds + i * 2048 + wid * 512);
        }
    };
    auto stageV = [&](int kt) {
#pragma unroll
        for (int i = 0; i < 4; i++) {
            int r = i * 16 + wid * 4 + (lane >> 4);
            int cs = (lane & 15) ^ (r & 7);
            gload16(Vbh + (size_t)r * 2048 + kt * KVB + cs * 8,
                    V_lds + i * 2048 + wid * 512);
        }
    };

    for (int pass = 0; pass < 2; ++pass) {
        int qt = pass ? (31 - jp) : jp;
        const unsigned short* Qb = Q + base_qk + (size_t)(qt * 64 + wid * 16) * E_DIM;
        short8 bq[2];
#pragma unroll
        for (int s2 = 0; s2 < 2; s2++)
            bq[s2] = *(const short8*)(Qb + (size_t)l15 * E_DIM + s2 * 32 + lg * 8);
        f32x4 acc_o[4] = {};
        float m_i = -1e30f, l_i = 0.f;
        int q_glob = qt * 64 + wid * 16 + l15;
        int nkt = (qt + 2) >> 1;
        stageK(0);
        stageV(0);
        asm volatile("s_waitcnt vmcnt(4)" ::: "memory");   // own K0 (and bq) done
        __builtin_amdgcn_s_barrier();                      // all waves' K0 landed
        __builtin_amdgcn_sched_barrier(0);
        for (int kt = 0; kt < nkt; ++kt) {
            f32x4 acc_s[8] = {};
            __builtin_amdgcn_s_setprio(1);
#pragma unroll
            for (int mf = 0; mf < 8; mf++) {
                int rK = mf * 16 + l15;
#pragma unroll
                for (int s2 = 0; s2 < 2; s2++) {
                    int gc = s2 * 4 + lg;
                    short8 a = *(const short8*)&K_lds[rK * 64 + ((gc ^ (rK & 7)) << 3)];
                    acc_s[mf] = __builtin_amdgcn_mfma_f32_16x16x32_bf16(
                        a, bq[s2], acc_s[mf], 0, 0, 0);
                }
            }
            __builtin_amdgcn_s_setprio(0);
            __builtin_amdgcn_s_barrier();       // B1: K_lds free
            if (kt + 1 < nkt) stageK(kt + 1);
            float sv[32];
            float vmax = -1e30f;
            if (kt == nkt - 1) {
#pragma unroll
                for (int mf = 0; mf < 8; mf++)
#pragma unroll
                    for (int r = 0; r < 4; r++) {
                        int kg = kt * KVB + mf * 16 + lg * 4 + r;
                        float v = acc_s[mf][r];
                        if (kg > q_glob) v = -1e30f;
                        sv[mf * 4 + r] = v;
                        vmax = fmaxf(vmax, v);
                    }
            } else {
#pragma unroll
                for (int mf = 0; mf < 8; mf++)
#pragma unroll
                    for (int r = 0; r < 4; r++) {
                        float v = acc_s[mf][r];
                        sv[mf * 4 + r] = v;
                        vmax = fmaxf(vmax, v);
                    }
            }
            vmax = fmaxf(vmax, __shfl_xor(vmax, 16));
            vmax = fmaxf(vmax, __shfl_xor(vmax, 32));
            float m_new = fmaxf(m_i, vmax);
            float corr = __expf(m_i - m_new);
            float rowsum = 0.f;
#pragma unroll
            for (int i = 0; i < 32; i++) {
                float p = __expf(sv[i] - m_new);
                sv[i] = p;
                rowsum += p;
            }
            rowsum += __shfl_xor(rowsum, 16);
            rowsum += __shfl_xor(rowsum, 32);
            l_i = l_i * corr + rowsum;
            m_i = m_new;
#pragma unroll
            for (int mf = 0; mf < 8; mf++) {
                ushort4_t pk;
#pragma unroll
                for (int r = 0; r < 4; r++) pk[r] = f2bf(sv[mf * 4 + r]);
                *(ushort4_t*)&P_lds[wid][l15][mf * 16 + lg * 4] = pk;
            }
#pragma unroll
            for (int r = 0; r < 4; r++) {
                float c4 = __shfl(corr, lg * 4 + r);
#pragma unroll
                for (int nf = 0; nf < 4; nf++) acc_o[nf][r] *= c4;
            }
            if (kt + 1 < nkt)
                asm volatile("s_waitcnt vmcnt(4)" ::: "memory");  // own V(kt) done
            else
                asm volatile("s_waitcnt vmcnt(0)" ::: "memory");
            __builtin_amdgcn_s_barrier();       // B2: all V(kt) landed
            __builtin_amdgcn_sched_barrier(0);
            __builtin_amdgcn_s_setprio(1);
#pragma unroll
            for (int s2 = 0; s2 < 4; s2++) {
                short8 pa = *(const short8*)&P_lds[wid][l15][s2 * 32 + lg * 8];
#pragma unroll
                for (int nf = 0; nf < 4; nf++) {
                    int rV = nf * 16 + l15;
                    int gc = s2 * 4 + lg;
                    short8 bv = *(const short8*)&V_lds[rV * 128 + ((gc ^ (rV & 7)) << 3)];
                    acc_o[nf] = __builtin_amdgcn_mfma_f32_16x16x32_bf16(
                        pa, bv, acc_o[nf], 0, 0, 0);
                }
            }
            __builtin_amdgcn_s_setprio(0);
            __builtin_amdgcn_s_barrier();       // B3: V_lds free
            if (kt + 1 < nkt) {
                stageV(kt + 1);
                asm volatile("s_waitcnt vmcnt(4)" ::: "memory");  // own K(kt+1) done
            }
            __builtin_amdgcn_s_barrier();       // B4: all K(kt+1) landed
            __builtin_amdgcn_sched_barrier(0);
        }
        unsigned short* Ob = O + base_qk + (size_t)(qt * 64 + wid * 16) * E_DIM;
#pragma unroll
        for (int r = 0; r < 4; r++) {
            float linv = 1.f / __shfl(l_i, lg * 4 + r);
#pragma unroll
            for (int nf = 0; nf < 4; nf++)
                Ob[(size_t)(lg * 4 + r) * E_DIM + nf * 16 + l15] =
                    f2bf(acc_o[nf][r] * linv);
        }
    }
}

extern "C" void kernel_launch(void* const* d_in, const int* in_sizes, int n_in,
                              void* d_out, int out_size, void* d_ws, size_t ws_size,
                              hipStream_t stream) {
    (void)in_sizes; (void)n_in; (void)out_size; (void)ws_size;
    const float* x  = (const float*)d_in[0];
    const float* Wq = (const float*)d_in[1];
    const float* Wk = (const float*)d_in[2];
    const float* Wv = (const float*)d_in[3];
    const float* Wo = (const float*)d_in[4];

    unsigned short* us = (unsigned short*)d_ws;
    unsigned short* xb    = us;                  // 4096x1024
    unsigned short* WqkvT = us + 4194304;        // 3072x1024 (Wq;Wk;Wv rows)
    unsigned short* WoT   = us + 7340032;        // 1024x1024
    unsigned short* Qb    = us + 8388608;        // 4096x1024 (roped+scaled)
    unsigned short* Kb    = us + 12582912;       // 4096x1024 (roped)
    unsigned short* Vt    = us + 16777216;       // [b][h][d][s] = [2][16][64][2048]
    unsigned short* AO    = us + 20971520;
    float* cosT = (float*)((char*)d_ws + 50331648);
    float* sinT = cosT + 65536;

    k_convert<<<2048, 256, 0, stream>>>(x, xb);
    k_transw<<<dim3(32, 32, 4), dim3(32, 8), 0, stream>>>(
        Wq, Wk, Wv, Wo, WqkvT, WqkvT + 1048576, WqkvT + 2097152, WoT);
    k_rope_table<<<256, 256, 0, stream>>>(cosT, sinT);
    k_gemmN<128, 64, 48, true><<<dim3(48, 32), 256, 0, stream>>>(
        xb, WqkvT, Qb, Kb, Vt, nullptr, cosT, sinT);
    k_attn<<<dim3(16, 32), 256, 0, stream>>>(Qb, Kb, Vt, AO);
    k_gemmN<128, 64, 16, false><<<dim3(16, 32), 256, 0, stream>>>(
        AO, WoT, nullptr, nullptr, nullptr, (float*)d_out, cosT, sinT);
}